// Round 1
// baseline (47070.740 us; speedup 1.0000x reference)
//
#include <hip/hip_runtime.h>
#include <math.h>
#include <stdint.h>

// ---------------- problem constants ----------------
#define NB   64     // batch
#define TE   256    // T_ENC
#define TD   200    // T_DEC
#define MR   160    // MEL*R
#define ATT  256
#define PRE1 256
#define PRE2 128

typedef _Float16 h2 __attribute__((ext_vector_type(2)));

__device__ __forceinline__ float dot2f(h2 a, h2 b, float c){
#if __has_builtin(__builtin_amdgcn_fdot2)
  return __builtin_amdgcn_fdot2(a, b, c, false);
#else
  return c + (float)a.x*(float)b.x + (float)a.y*(float)b.y;
#endif
}

__device__ __forceinline__ float sigmf(float x){
  return __fdividef(1.f, 1.f + __expf(-x));
}
__device__ __forceinline__ float tanhf_(float x){
  float ax = fabsf(x);
  float e  = __expf(-2.f*ax);
  float r  = __fdividef(1.f - e, 1.f + e);
  return copysignf(r, x);
}

// ---------------- workspace layout (bytes) ----------------
static constexpr size_t OFF_PM   = 0;                                   // f16 [B][256 d][256 t']
static constexpr size_t OFF_ENCH = OFF_PM   + (size_t)NB*256*TE*2;      // f16 [B][t'][d]
static constexpr size_t OFF_GIP  = OFF_ENCH + (size_t)NB*TE*256*2;      // f16 [B][TD][768]
static constexpr size_t OFF_P    = OFF_GIP  + (size_t)NB*TD*768*2;      // f16 [B][TD][512]
static constexpr size_t OFF_W    = OFF_P    + (size_t)NB*TD*512*2;      // f16 weights (h2-interleaved)

// weight sub-offsets in h2 (4-byte) units
static constexpr size_t W_ATTC = 0;        // att_wih ctx part: [kp<128][768]
static constexpr size_t W_ATTH = 98304;    // att_whh:          [kp<128][768]
static constexpr size_t W_QW   = 196608;   // q_w:              [kp<128][256]
static constexpr size_t W_PROJ = 229376;   // proj_w:           [kp<256][256]
static constexpr size_t W_G1I  = 294912;
static constexpr size_t W_G1H  = 393216;
static constexpr size_t W_G2I  = 491520;
static constexpr size_t W_G2H  = 589824;
static constexpr size_t W_PW1  = 688128;   // pre_w1: [kp<80][256]
static constexpr size_t W_PW2  = 708608;   // pre_w2: [kp<128][128]
static constexpr size_t W_WIHP = 724992;   // att_wih pre part: [kp<64][768]
static constexpr size_t W_MEMW = 774144;   // mem_w: [kp<128][256]
static constexpr size_t W_MELW = 806912;   // mel_w: [kp<256][160]
static constexpr size_t W_END  = 847872;   // h2 units
static constexpr size_t WS_NEEDED = OFF_W + W_END*4;

// ---------------- K1: f32 (O,K) row-major -> f16 h2-interleaved [kp][O] ----------------
__global__ void k_conv(const float* __restrict__ src, char* __restrict__ ws,
                       unsigned off_h2, int O, int Kh, int k0, int ld){
  int i = blockIdx.x*256 + threadIdx.x;
  if (i >= O*Kh) return;
  int o = i % O, kp = i / O;
  _Float16* dst = (_Float16*)(ws + OFF_W) + 2*(size_t)off_h2;
  dst[2*i    ] = (_Float16)src[(size_t)o*ld + k0 + 2*kp    ];
  dst[2*i + 1] = (_Float16)src[(size_t)o*ld + k0 + 2*kp + 1];
}

// ---------------- K2: processed_memory (transposed, f16) + enc f16 copy ----------------
__global__ void k_pm(const float* __restrict__ enc, char* __restrict__ ws){
  int bt = blockIdx.x;             // b*256 + t
  int b  = bt >> 8, t = bt & 255;
  int j  = threadIdx.x;
  const h2* mw = (const h2*)(ws + OFF_W) + W_MEMW;
  _Float16* pmT  = (_Float16*)(ws + OFF_PM);
  _Float16* encH = (_Float16*)(ws + OFF_ENCH);
  __shared__ _Float16 e[256];
  float ev = enc[(size_t)bt*256 + j];
  e[j] = (_Float16)ev;
  encH[(size_t)bt*256 + j] = (_Float16)ev;
  __syncthreads();
  const h2* e2 = (const h2*)e;
  float acc = 0.f;
  #pragma unroll 8
  for (int kp=0; kp<128; ++kp) acc = dot2f(mw[kp*256 + j], e2[kp], acc);
  pmT[(size_t)b*TE*256 + (size_t)j*TE + t] = (_Float16)acc;
}

// ---------------- K3: prenet + gi_pre (all timesteps, parallel) ----------------
__global__ void k_pre(const float* __restrict__ xin, const float* __restrict__ b1,
                      const float* __restrict__ b2, const float* __restrict__ bih,
                      char* __restrict__ ws){
  int bt = blockIdx.x;             // b*TD + t
  int b = bt / TD, t = bt % TD;
  int j = threadIdx.x;
  const h2* w1 = (const h2*)(ws + OFF_W) + W_PW1;
  const h2* w2 = (const h2*)(ws + OFF_W) + W_PW2;
  const h2* wp = (const h2*)(ws + OFF_W) + W_WIHP;
  _Float16* gip = (_Float16*)(ws + OFF_GIP) + (size_t)bt*768;
  __shared__ _Float16 xh[160];
  __shared__ _Float16 a1[256];
  __shared__ _Float16 pr[128];
  if (j < 160)
    xh[j] = (t==0) ? (_Float16)0.f : (_Float16)xin[((size_t)b*TD + (t-1))*MR + j];
  __syncthreads();
  { // prenet layer 1 (relu)
    const h2* x2 = (const h2*)xh;
    float acc = b1[j];
    #pragma unroll 8
    for (int kp=0; kp<80; ++kp) acc = dot2f(w1[kp*256 + j], x2[kp], acc);
    a1[j] = (_Float16)fmaxf(acc, 0.f);
  }
  __syncthreads();
  if (j < 128){ // prenet layer 2 (relu)
    const h2* x2 = (const h2*)a1;
    float acc = b2[j];
    #pragma unroll 8
    for (int kp=0; kp<128; ++kp) acc = dot2f(w2[kp*128 + j], x2[kp], acc);
    pr[j] = (_Float16)fmaxf(acc, 0.f);
  }
  __syncthreads();
  { // gi_pre = pre @ wih_pre.T + bih
    const h2* p2 = (const h2*)pr;
    for (int o=j; o<768; o+=256){
      float acc = bih[o];
      #pragma unroll 8
      for (int kp=0; kp<64; ++kp) acc = dot2f(wp[kp*768 + o], p2[kp], acc);
      gip[o] = (_Float16)acc;
    }
  }
}

// ---------------- fused dual-GEMV partial (6 streams) for GRU stages ----------------
__device__ __forceinline__ void gemv6(const h2* __restrict__ wa, const h2* __restrict__ wb,
                                      const _Float16* xa, const _Float16* xb,
                                      int j, int half, float acc[6]){
  const h2* x2a = (const h2*)xa;
  const h2* x2b = (const h2*)xb;
  float a0=0.f,a1=0.f,a2=0.f,b0=0.f,b1=0.f,b2=0.f;
  const int kp0 = half*64;
  #pragma unroll 8
  for (int k=0; k<64; ++k){
    int kp = kp0 + k;
    h2 xva = x2a[kp], xvb = x2b[kp];
    int idx = kp*768 + j;
    a0 = dot2f(wa[idx      ], xva, a0);
    a1 = dot2f(wa[idx + 256], xva, a1);
    a2 = dot2f(wa[idx + 512], xva, a2);
    b0 = dot2f(wb[idx      ], xvb, b0);
    b1 = dot2f(wb[idx + 256], xvb, b1);
    b2 = dot2f(wb[idx + 512], xvb, b2);
  }
  acc[0]=a0; acc[1]=a1; acc[2]=a2; acc[3]=b0; acc[4]=b1; acc[5]=b2;
}

// ---------------- K4: the serial decoder (one block per batch element) ----------------
__global__ __launch_bounds__(512) void k_dec(
    const int*   __restrict__ memlen,
    const float* __restrict__ att_bhh,
    const float* __restrict__ vw,
    const float* __restrict__ proj_b,
    const float* __restrict__ g1_bih, const float* __restrict__ g1_bhh,
    const float* __restrict__ g2_bih, const float* __restrict__ g2_bhh,
    float* __restrict__ out, char* __restrict__ ws)
{
  const int tid  = threadIdx.x;
  const int j    = tid & 255;
  const int half = tid >> 8;           // split-K half
  const int b    = blockIdx.x;

  const h2*       wAll = (const h2*)(ws + OFF_W);
  const _Float16* pmT  = (const _Float16*)(ws + OFF_PM)   + (size_t)b*TE*256; // [d][t']
  const _Float16* encH = (const _Float16*)(ws + OFF_ENCH) + (size_t)b*TE*256; // [t'][d]
  const _Float16* gipB = (const _Float16*)(ws + OFF_GIP)  + (size_t)b*TD*768;
  _Float16*       pst  = (_Float16*)(ws + OFF_P)          + (size_t)b*TD*512;
  float* outAttn = out + (size_t)NB*TD*MR + (size_t)b*TD*TE;

  __shared__ float hAf[256], h1f[256], h2f[256], df[256], qf[256], sc[256];
  __shared__ float part[256][7];
  __shared__ float vl[256];
  __shared__ float red[8];
  __shared__ _Float16 hAh[256], ctxh[256], h1h[256], h2h[256], dh[256];

  if (tid < 256){
    hAf[j]=0.f; h1f[j]=0.f; h2f[j]=0.f; df[j]=0.f;
    hAh[j]=(_Float16)0.f; ctxh[j]=(_Float16)0.f;
    h1h[j]=(_Float16)0.f; h2h[j]=(_Float16)0.f; dh[j]=(_Float16)0.f;
    vl[j]=vw[j];
  }
  const int ml = memlen[b];
  __syncthreads();

  #pragma unroll 1
  for (int t=0; t<TD; ++t){
    //==== S1: attention GRU : gi_ctx & gh fused ====
    {
      float a[6];
      gemv6(wAll + W_ATTC, wAll + W_ATTH, ctxh, hAh, j, half, a);
      if (half){
        #pragma unroll
        for (int i=0;i<6;++i) part[j][i]=a[i];
      }
      __syncthreads();
      if (!half){
        const _Float16* gip = gipB + (size_t)t*768;
        float gir = a[0]+part[j][0] + (float)gip[j];
        float giz = a[1]+part[j][1] + (float)gip[256+j];
        float gin = a[2]+part[j][2] + (float)gip[512+j];
        float ghr = a[3]+part[j][3] + att_bhh[j];
        float ghz = a[4]+part[j][4] + att_bhh[256+j];
        float ghn = a[5]+part[j][5] + att_bhh[512+j];
        float r = sigmf(gir+ghr), z = sigmf(giz+ghz);
        float n = tanhf_(gin + r*ghn);
        float hn = (1.f-z)*n + z*hAf[j];
        hAf[j]=hn; hAh[j]=(_Float16)hn;
      }
      __syncthreads();
    }
    //==== S2a: q = h_att @ q_w.T ====
    {
      const h2* wq = wAll + W_QW;
      const h2* x2 = (const h2*)hAh;
      float a=0.f; const int kp0 = half*64;
      #pragma unroll 8
      for (int k=0;k<64;++k){ int kp=kp0+k; a = dot2f(wq[kp*256 + j], x2[kp], a); }
      if (half) part[j][0]=a;
      __syncthreads();
      if (!half) qf[j] = a + part[j][0];
      __syncthreads();
    }
    //==== S2b: score[t'=j] = sum_d v[d]*tanh(pm[d][j] + q[d]) ====
    {
      float s=0.f; const int d0 = half*128;
      #pragma unroll 4
      for (int k=0;k<128;++k){
        int d = d0+k;
        float pv = (float)pmT[(size_t)d*TE + j];
        s += vl[d]*tanhf_(pv + qf[d]);
      }
      if (half) part[j][0]=s;
      __syncthreads();
      if (!half){
        s += part[j][0];
        sc[j] = (j < ml) ? s : -INFINITY;
      }
      __syncthreads();
    }
    //==== S2c: softmax + attention-weights output ====
    {
      float v = (tid<256) ? sc[j] : -INFINITY;
      #pragma unroll
      for (int o=32;o>0;o>>=1) v = fmaxf(v, __shfl_down(v,o,64));
      if ((tid&63)==0) red[tid>>6]=v;
      __syncthreads();
      float m = red[0];
      #pragma unroll
      for (int i=1;i<8;++i) m = fmaxf(m, red[i]);
      __syncthreads();
      float e = (tid<256) ? __expf(sc[j]-m) : 0.f;
      float sv = e;
      #pragma unroll
      for (int o=32;o>0;o>>=1) sv += __shfl_down(sv,o,64);
      if ((tid&63)==0) red[tid>>6]=sv;
      __syncthreads();
      float sum = red[0];
      #pragma unroll
      for (int i=1;i<8;++i) sum += red[i];
      float inv = __fdividef(1.f, sum);
      if (tid<256){
        float al = e*inv;
        sc[j] = al;
        outAttn[(size_t)t*TE + j] = al;
      }
      __syncthreads();
    }
    //==== S2d: ctx[d=j] = sum_t' align[t']*enc[t'][d] ====
    {
      float c=0.f; const int t0 = half*128;
      #pragma unroll 4
      for (int k=0;k<128;++k){
        int tp = t0+k;
        c += sc[tp]*(float)encH[(size_t)tp*256 + j];
      }
      if (half) part[j][0]=c;
      __syncthreads();
      if (!half) ctxh[j] = (_Float16)(c + part[j][0]);
      __syncthreads();
    }
    //==== S3: d = [h_att, ctx] @ proj_w.T + proj_b ====
    {
      const h2* wp = wAll + W_PROJ;
      const h2* x2 = half ? (const h2*)ctxh : (const h2*)hAh;
      const int kb = half*128;
      float a=0.f;
      #pragma unroll 8
      for (int k=0;k<128;++k) a = dot2f(wp[(kb+k)*256 + j], x2[k], a);
      if (half) part[j][0]=a;
      __syncthreads();
      if (!half){
        float dv = a + part[j][0] + proj_b[j];
        df[j]=dv; dh[j]=(_Float16)dv;
      }
      __syncthreads();
    }
    //==== S4: GRU1 + residual ====
    {
      float a[6];
      gemv6(wAll + W_G1I, wAll + W_G1H, dh, h1h, j, half, a);
      if (half){
        #pragma unroll
        for (int i=0;i<6;++i) part[j][i]=a[i];
      }
      __syncthreads();
      if (!half){
        float gir=a[0]+part[j][0]+g1_bih[j];
        float giz=a[1]+part[j][1]+g1_bih[256+j];
        float gin=a[2]+part[j][2]+g1_bih[512+j];
        float ghr=a[3]+part[j][3]+g1_bhh[j];
        float ghz=a[4]+part[j][4]+g1_bhh[256+j];
        float ghn=a[5]+part[j][5]+g1_bhh[512+j];
        float r=sigmf(gir+ghr), z=sigmf(giz+ghz);
        float n=tanhf_(gin + r*ghn);
        float hn=(1.f-z)*n + z*h1f[j];
        float dn = hn + df[j];
        h1f[j]=hn; h1h[j]=(_Float16)hn;
        df[j]=dn;  dh[j]=(_Float16)dn;
      }
      __syncthreads();
    }
    //==== S5: GRU2 + residual ====
    {
      float a[6];
      gemv6(wAll + W_G2I, wAll + W_G2H, dh, h2h, j, half, a);
      if (half){
        #pragma unroll
        for (int i=0;i<6;++i) part[j][i]=a[i];
      }
      __syncthreads();
      if (!half){
        float gir=a[0]+part[j][0]+g2_bih[j];
        float giz=a[1]+part[j][1]+g2_bih[256+j];
        float gin=a[2]+part[j][2]+g2_bih[512+j];
        float ghr=a[3]+part[j][3]+g2_bhh[j];
        float ghz=a[4]+part[j][4]+g2_bhh[256+j];
        float ghn=a[5]+part[j][5]+g2_bhh[512+j];
        float r=sigmf(gir+ghr), z=sigmf(giz+ghz);
        float n=tanhf_(gin + r*ghn);
        float hn=(1.f-z)*n + z*h2f[j];
        float dn = hn + df[j];
        h2f[j]=hn; h2h[j]=(_Float16)hn;
        df[j]=dn;  dh[j]=(_Float16)dn;
      }
      __syncthreads();
    }
    //==== S6: stash p = [d, ctx] for the parallel mel/stop pass ====
    if (!half){
      pst[(size_t)t*512 + j]       = dh[j];
      pst[(size_t)t*512 + 256 + j] = ctxh[j];
    }
  }
}

// ---------------- K5: mel + stop projections (parallel over b,t) ----------------
__global__ void k_post(const float* __restrict__ mel_b, const float* __restrict__ stop_w,
                       const float* __restrict__ stop_b, float* __restrict__ out,
                       char* __restrict__ ws){
  int bt = blockIdx.x;             // b*TD + t
  int b = bt / TD, t = bt % TD;
  int j = threadIdx.x;
  const h2* wm = (const h2*)(ws + OFF_W) + W_MELW;
  const _Float16* p = (const _Float16*)(ws + OFF_P) + (size_t)bt*512;
  __shared__ _Float16 pl[512];
  ((uint32_t*)pl)[j] = ((const uint32_t*)p)[j];
  __syncthreads();
  const h2* p2 = (const h2*)pl;
  if (j < 160){
    float acc = mel_b[j];
    #pragma unroll 8
    for (int kp=0; kp<256; ++kp) acc = dot2f(wm[kp*160 + j], p2[kp], acc);
    out[(size_t)bt*MR + j] = acc;
  } else if (j == 160){
    float acc = stop_b[0];
    for (int k=0; k<512; ++k) acc += stop_w[k]*(float)pl[k];
    float s = __fdividef(1.f, 1.f + __expf(-acc));
    float* os = out + (size_t)NB*TD*MR + (size_t)NB*TD*TE + (size_t)b*2*TD;
    os[2*t]   = s;
    os[2*t+1] = s;
  }
}

// ---------------- host ----------------
extern "C" void kernel_launch(void* const* d_in, const int* in_sizes, int n_in,
                              void* d_out, int out_size, void* d_ws, size_t ws_size,
                              hipStream_t stream)
{
  const float* enc     = (const float*)d_in[0];
  const float* xin     = (const float*)d_in[1];
  const int*   mlen    = (const int*)  d_in[2];
  const float* pre_w1  = (const float*)d_in[3];
  const float* pre_b1  = (const float*)d_in[4];
  const float* pre_w2  = (const float*)d_in[5];
  const float* pre_b2  = (const float*)d_in[6];
  const float* mem_w   = (const float*)d_in[7];
  const float* att_wih = (const float*)d_in[8];
  const float* att_whh = (const float*)d_in[9];
  const float* att_bih = (const float*)d_in[10];
  const float* att_bhh = (const float*)d_in[11];
  const float* q_w     = (const float*)d_in[12];
  const float* v_w     = (const float*)d_in[13];
  const float* proj_w  = (const float*)d_in[14];
  const float* proj_b  = (const float*)d_in[15];
  const float* g1_wih  = (const float*)d_in[16];
  const float* g1_whh  = (const float*)d_in[17];
  const float* g1_bih  = (const float*)d_in[18];
  const float* g1_bhh  = (const float*)d_in[19];
  const float* g2_wih  = (const float*)d_in[20];
  const float* g2_whh  = (const float*)d_in[21];
  const float* g2_bih  = (const float*)d_in[22];
  const float* g2_bhh  = (const float*)d_in[23];
  const float* mel_w   = (const float*)d_in[24];
  const float* mel_b   = (const float*)d_in[25];
  const float* stop_w  = (const float*)d_in[26];
  const float* stop_b  = (const float*)d_in[27];
  (void)in_sizes; (void)n_in; (void)out_size;

  if (ws_size < WS_NEEDED) return;   // cannot run without scratch

  float* out = (float*)d_out;
  char*  ws  = (char*)d_ws;

  auto conv = [&](const float* src, size_t off_h2, int O, int Kh, int k0, int ld){
    int n = O*Kh;
    k_conv<<<(n+255)/256, 256, 0, stream>>>(src, ws, (unsigned)off_h2, O, Kh, k0, ld);
  };
  conv(att_wih, W_ATTC, 768, 128, 128, 384);
  conv(att_whh, W_ATTH, 768, 128, 0,   256);
  conv(q_w,     W_QW,   256, 128, 0,   256);
  conv(proj_w,  W_PROJ, 256, 256, 0,   512);
  conv(g1_wih,  W_G1I,  768, 128, 0,   256);
  conv(g1_whh,  W_G1H,  768, 128, 0,   256);
  conv(g2_wih,  W_G2I,  768, 128, 0,   256);
  conv(g2_whh,  W_G2H,  768, 128, 0,   256);
  conv(pre_w1,  W_PW1,  256, 80,  0,   160);
  conv(pre_w2,  W_PW2,  128, 128, 0,   256);
  conv(att_wih, W_WIHP, 768, 64,  0,   384);
  conv(mem_w,   W_MEMW, 256, 128, 0,   256);
  conv(mel_w,   W_MELW, 160, 256, 0,   512);

  k_pm <<<NB*TE, 256, 0, stream>>>(enc, ws);
  k_pre<<<NB*TD, 256, 0, stream>>>(xin, pre_b1, pre_b2, att_bih, ws);
  k_dec<<<NB, 512, 0, stream>>>(mlen, att_bhh, v_w, proj_b,
                                g1_bih, g1_bhh, g2_bih, g2_bhh, out, ws);
  k_post<<<NB*TD, 256, 0, stream>>>(mel_b, stop_w, stop_b, out, ws);
}

// Round 3
// 10766.342 us; speedup vs baseline: 4.3720x; 4.3720x over previous
//
#include <hip/hip_runtime.h>
#include <math.h>
#include <stdint.h>

// ---------------- problem constants ----------------
#define NB   64
#define TE   256
#define TD   200
#define MR   160

typedef _Float16 h2 __attribute__((ext_vector_type(2)));

__device__ __forceinline__ float dot2f(h2 a, h2 b, float c){
  return __builtin_amdgcn_fdot2(a, b, c, false);
}
__device__ __forceinline__ h2 u2h(unsigned int u){ return __builtin_bit_cast(h2, u); }
__device__ __forceinline__ unsigned int h2u(h2 h){ return __builtin_bit_cast(unsigned int, h); }

__device__ __forceinline__ float sigmf(float x){
  return __fdividef(1.f, 1.f + __expf(-x));
}
__device__ __forceinline__ float tanhf_(float x){
  float ax = fabsf(x);
  float e  = __expf(-2.f*ax);
  float r  = __fdividef(1.f - e, 1.f + e);
  return copysignf(r, x);
}

// ---------------- workspace layout (bytes) ----------------
static constexpr size_t OFF_PM   = 0;                       // f16 [B][256 d][256 t']
static constexpr size_t OFF_ENCH = 8388608;                 // f16 [B][t'][256 d]
static constexpr size_t OFF_GIP  = 16777216;                // f16 [B][TD][768]
static constexpr size_t OFF_P    = 36438016;                // f16 [B][TD][512]
static constexpr size_t OFF_W2   = 49545216;                // h2 pool (small mats)
static constexpr size_t OFF_W8   = 50184192;                // uint4 pool (k_dec mats)
static constexpr size_t WS_NEEDED = 52936704;

// pool A (h2 slots): [kp][O] layouts for aux kernels
static constexpr size_t A_PW1  = 0;        // [80 kp][256]
static constexpr size_t A_PW2  = 20480;    // [128 kp][128]
static constexpr size_t A_WIHP = 36864;    // [64 kp][768]
static constexpr size_t A_MEMW = 86016;    // [128 kp][256]
static constexpr size_t A_MELW = 118784;   // [256 kp][160]

// pool B (uint4 slots): [kq][O] with 8 f16 per slot
static constexpr size_t B_ATTC = 0;        // [32 kq][768]
static constexpr size_t B_ATTH = 24576;
static constexpr size_t B_G1I  = 49152;
static constexpr size_t B_G1H  = 73728;
static constexpr size_t B_G2I  = 98304;
static constexpr size_t B_G2H  = 122880;
static constexpr size_t B_PROJ = 147456;   // [64 kq][256]
static constexpr size_t B_QW   = 163840;   // [32 kq][256]

// ---------------- K1a: f32 (O,K) row-major -> f16 [kp][O] (pool A) ----------------
__global__ void k_conv(const float* __restrict__ src, char* __restrict__ ws,
                       unsigned off_h2, int O, int Kh, int k0, int ld){
  int i = blockIdx.x*256 + threadIdx.x;
  if (i >= O*Kh) return;
  int o = i % O, kp = i / O;
  _Float16* dst = (_Float16*)(ws + OFF_W2) + 2*((size_t)off_h2 + i);
  dst[0] = (_Float16)src[(size_t)o*ld + k0 + 2*kp    ];
  dst[1] = (_Float16)src[(size_t)o*ld + k0 + 2*kp + 1];
}

// ---------------- K1b: f32 (O,K) row-major -> f16 [kq][O] packed x8 (pool B) ----------------
__global__ void k_conv8(const float* __restrict__ src, char* __restrict__ ws,
                        unsigned off16, int O, int Kq, int k0, int ld){
  int i = blockIdx.x*256 + threadIdx.x;
  if (i >= O*Kq) return;
  int o = i % O, kq = i / O;
  const float* s = src + (size_t)o*ld + k0 + kq*8;
  h2 p0, p1, p2, p3;
  p0.x=(_Float16)s[0]; p0.y=(_Float16)s[1];
  p1.x=(_Float16)s[2]; p1.y=(_Float16)s[3];
  p2.x=(_Float16)s[4]; p2.y=(_Float16)s[5];
  p3.x=(_Float16)s[6]; p3.y=(_Float16)s[7];
  uint4 r; r.x=h2u(p0); r.y=h2u(p1); r.z=h2u(p2); r.w=h2u(p3);
  ((uint4*)(ws + OFF_W8))[(size_t)off16 + i] = r;
}

// ---------------- K2: processed_memory (pmT [b][d][t']) + enc f16 copy ----------------
__global__ void k_pm(const float* __restrict__ enc, char* __restrict__ ws){
  int bt = blockIdx.x;             // b*256 + t
  int b  = bt >> 8, t = bt & 255;
  int j  = threadIdx.x;
  const h2* mw = (const h2*)(ws + OFF_W2) + A_MEMW;
  _Float16* pmT  = (_Float16*)(ws + OFF_PM);
  _Float16* encH = (_Float16*)(ws + OFF_ENCH);
  __shared__ _Float16 e[256];
  float ev = enc[(size_t)bt*256 + j];
  e[j] = (_Float16)ev;
  encH[(size_t)bt*256 + j] = (_Float16)ev;
  __syncthreads();
  const h2* e2 = (const h2*)e;
  float acc = 0.f;
  #pragma unroll 8
  for (int kp=0; kp<128; ++kp) acc = dot2f(mw[kp*256 + j], e2[kp], acc);
  pmT[(size_t)b*TE*256 + (size_t)j*TE + t] = (_Float16)acc;
}

// ---------------- K3: prenet + gi_pre (all timesteps, parallel) ----------------
__global__ void k_pre(const float* __restrict__ xin, const float* __restrict__ b1,
                      const float* __restrict__ b2, const float* __restrict__ bih,
                      char* __restrict__ ws){
  int bt = blockIdx.x;             // b*TD + t
  int b = bt / TD, t = bt % TD;
  int j = threadIdx.x;
  const h2* w1 = (const h2*)(ws + OFF_W2) + A_PW1;
  const h2* w2 = (const h2*)(ws + OFF_W2) + A_PW2;
  const h2* wp = (const h2*)(ws + OFF_W2) + A_WIHP;
  _Float16* gip = (_Float16*)(ws + OFF_GIP) + (size_t)bt*768;
  __shared__ _Float16 xh[160];
  __shared__ _Float16 a1[256];
  __shared__ _Float16 pr[128];
  if (j < 160)
    xh[j] = (t==0) ? (_Float16)0.f : (_Float16)xin[((size_t)b*TD + (t-1))*MR + j];
  __syncthreads();
  {
    const h2* x2 = (const h2*)xh;
    float acc = b1[j];
    #pragma unroll 8
    for (int kp=0; kp<80; ++kp) acc = dot2f(w1[kp*256 + j], x2[kp], acc);
    a1[j] = (_Float16)fmaxf(acc, 0.f);
  }
  __syncthreads();
  if (j < 128){
    const h2* x2 = (const h2*)a1;
    float acc = b2[j];
    #pragma unroll 8
    for (int kp=0; kp<128; ++kp) acc = dot2f(w2[kp*128 + j], x2[kp], acc);
    pr[j] = (_Float16)fmaxf(acc, 0.f);
  }
  __syncthreads();
  {
    const h2* p2 = (const h2*)pr;
    for (int o=j; o<768; o+=256){
      float acc = bih[o];
      #pragma unroll 8
      for (int kp=0; kp<64; ++kp) acc = dot2f(wp[kp*768 + o], p2[kp], acc);
      gip[o] = (_Float16)acc;
    }
  }
}

// ---------------- k_dec helpers ----------------
__device__ __forceinline__ float d4dot(uint4 w, uint4 x, float a){
  a = dot2f(u2h(w.x), u2h(x.x), a);
  a = dot2f(u2h(w.y), u2h(x.y), a);
  a = dot2f(u2h(w.z), u2h(x.z), a);
  a = dot2f(u2h(w.w), u2h(x.w), a);
  return a;
}

// fused dual-operand 6-stream GEMV partials: thread (ks, j) covers 8 kq (=64 feats)
__device__ __forceinline__ void gemv6(const uint4* __restrict__ wI, const uint4* __restrict__ wH,
                                      const uint4* xI, const uint4* xH,
                                      int j, int ks, float* scr, int tid){
  float a0=0.f,a1=0.f,a2=0.f,a3=0.f,a4=0.f,a5=0.f;
  #pragma unroll 2
  for (int kq=ks*8; kq<ks*8+8; ++kq){
    uint4 xi = xI[kq];
    uint4 xh = xH[kq];
    uint4 w0 = wI[kq*768 +       j];
    uint4 w1 = wI[kq*768 + 256 + j];
    uint4 w2 = wI[kq*768 + 512 + j];
    a0 = d4dot(w0, xi, a0);
    a1 = d4dot(w1, xi, a1);
    a2 = d4dot(w2, xi, a2);
    uint4 w3 = wH[kq*768 +       j];
    uint4 w4 = wH[kq*768 + 256 + j];
    uint4 w5 = wH[kq*768 + 512 + j];
    a3 = d4dot(w3, xh, a3);
    a4 = d4dot(w4, xh, a4);
    a5 = d4dot(w5, xh, a5);
  }
  float* r = scr + tid*6;
  r[0]=a0; r[1]=a1; r[2]=a2; r[3]=a3; r[4]=a4; r[5]=a5;
}

// ---------------- K4: serial decoder, one block per batch, 1024 threads ----------------
__global__ __launch_bounds__(1024) void k_dec(
    const int*   __restrict__ memlen,
    const float* __restrict__ att_bhh,
    const float* __restrict__ vw,
    const float* __restrict__ proj_b,
    const float* __restrict__ g1_bih, const float* __restrict__ g1_bhh,
    const float* __restrict__ g2_bih, const float* __restrict__ g2_bhh,
    float* __restrict__ out, char* __restrict__ ws)
{
  const int tid = threadIdx.x;
  const int b   = blockIdx.x;
  const int ks  = tid >> 8;       // split-K quarter
  const int j   = tid & 255;      // output / t' index

  const uint4* W8   = (const uint4*)(ws + OFF_W8);
  const uint4* wAC  = W8 + B_ATTC;
  const uint4* wAH  = W8 + B_ATTH;
  const uint4* wG1I = W8 + B_G1I;
  const uint4* wG1H = W8 + B_G1H;
  const uint4* wG2I = W8 + B_G2I;
  const uint4* wG2H = W8 + B_G2H;
  const uint4* wPRJ = W8 + B_PROJ;
  const uint4* wQ   = W8 + B_QW;

  const _Float16* pmB  = (const _Float16*)(ws + OFF_PM)   + (size_t)b*TE*256;
  const unsigned* encW = (const unsigned*)(ws + OFF_ENCH) + (size_t)b*TE*128;
  const _Float16* gipB = (const _Float16*)(ws + OFF_GIP)  + (size_t)b*TD*768;
  _Float16*       pstB = (_Float16*)(ws + OFF_P)          + (size_t)b*TD*512;
  float* outA = out + (size_t)NB*TD*MR + (size_t)b*TD*TE;

  __shared__ __align__(16) _Float16 hAh[256], ctxh[256], h1h[256], h2h[256], dh[256];
  __shared__ float hAf[256], h1f[256], h2f[256], df[256];
  __shared__ float qf[256], sc[256], al[256], vl[256];
  __shared__ float scr[6144];
  __shared__ float red2[4];

  if (tid < 256){
    hAh[tid]=(_Float16)0.f; ctxh[tid]=(_Float16)0.f; h1h[tid]=(_Float16)0.f;
    h2h[tid]=(_Float16)0.f; dh[tid]=(_Float16)0.f;
    hAf[tid]=0.f; h1f[tid]=0.f; h2f[tid]=0.f; df[tid]=0.f;
    vl[tid]=vw[tid];
  }
  const int ml = memlen[b];
  __syncthreads();

  const uint4* hA4  = (const uint4*)hAh;
  const uint4* ctx4 = (const uint4*)ctxh;
  const uint4* h14  = (const uint4*)h1h;
  const uint4* h24  = (const uint4*)h2h;
  const uint4* dd4  = (const uint4*)dh;

  #pragma unroll 1
  for (int t=0; t<TD; ++t){
    //==== S1: attention GRU (xI = ctx(t-1), xH = hA(t-1)) ====
    gemv6(wAC, wAH, ctx4, hA4, j, ks, scr, tid);
    __syncthreads();
    if (tid < 256){
      const _Float16* gp = gipB + (size_t)t*768;
      float s0 = scr[tid*6+0]+scr[(256+tid)*6+0]+scr[(512+tid)*6+0]+scr[(768+tid)*6+0];
      float s1 = scr[tid*6+1]+scr[(256+tid)*6+1]+scr[(512+tid)*6+1]+scr[(768+tid)*6+1];
      float s2 = scr[tid*6+2]+scr[(256+tid)*6+2]+scr[(512+tid)*6+2]+scr[(768+tid)*6+2];
      float s3 = scr[tid*6+3]+scr[(256+tid)*6+3]+scr[(512+tid)*6+3]+scr[(768+tid)*6+3];
      float s4 = scr[tid*6+4]+scr[(256+tid)*6+4]+scr[(512+tid)*6+4]+scr[(768+tid)*6+4];
      float s5 = scr[tid*6+5]+scr[(256+tid)*6+5]+scr[(512+tid)*6+5]+scr[(768+tid)*6+5];
      float gir = s0 + (float)gp[tid];
      float giz = s1 + (float)gp[256+tid];
      float gin = s2 + (float)gp[512+tid];
      float ghr = s3 + att_bhh[tid];
      float ghz = s4 + att_bhh[256+tid];
      float ghn = s5 + att_bhh[512+tid];
      float r = sigmf(gir+ghr), z = sigmf(giz+ghz);
      float n = tanhf_(gin + r*ghn);
      float h = (1.f-z)*n + z*hAf[tid];
      hAf[tid]=h; hAh[tid]=(_Float16)h;
    }
    __syncthreads();
    //==== S2: q = hA @ q_w.T ====
    {
      float a=0.f;
      #pragma unroll 2
      for (int kq=ks*8; kq<ks*8+8; ++kq)
        a = d4dot(wQ[kq*256 + j], hA4[kq], a);
      scr[tid]=a;
    }
    __syncthreads();
    if (tid<256) qf[tid] = scr[tid]+scr[256+tid]+scr[512+tid]+scr[768+tid];
    __syncthreads();
    //==== S3: score[t'=j] partials over d ====
    {
      const int d0 = ks*64;
      float s=0.f;
      #pragma unroll 8
      for (int d=d0; d<d0+64; ++d){
        float pv = (float)pmB[(size_t)d*TE + j];
        s += vl[d]*tanhf_(pv + qf[d]);
      }
      scr[tid]=s;
    }
    __syncthreads();
    if (tid<256){
      float s = scr[tid]+scr[256+tid]+scr[512+tid]+scr[768+tid];
      sc[tid] = (tid < ml) ? s : -INFINITY;
    }
    __syncthreads();
    //==== S4: softmax (first 4 waves) ====
    {
      float v = (tid<256) ? sc[tid] : -INFINITY;
      if (tid<256){
        #pragma unroll
        for (int o=32;o>0;o>>=1) v = fmaxf(v, __shfl_down(v,o,64));
        if ((tid&63)==0) red2[tid>>6]=v;
      }
      __syncthreads();
      float m = fmaxf(fmaxf(red2[0],red2[1]), fmaxf(red2[2],red2[3]));
      __syncthreads();
      float e = 0.f;
      if (tid<256){
        e = __expf(sc[tid]-m);
        float sv = e;
        #pragma unroll
        for (int o=32;o>0;o>>=1) sv += __shfl_down(sv,o,64);
        if ((tid&63)==0) red2[tid>>6]=sv;
      }
      __syncthreads();
      if (tid<256){
        float sum = red2[0]+red2[1]+red2[2]+red2[3];
        float a = e*__fdividef(1.f,sum);
        al[tid]=a;
        outA[(size_t)t*TE + tid]=a;
      }
    }
    __syncthreads();
    //==== S5: ctx[d] = sum_t' al[t']*enc[t'][d] ====
    {
      const int tsl = tid>>7, dp = tid&127;
      float c0=0.f, c1=0.f;
      #pragma unroll 8
      for (int tp=tsl*32; tp<tsl*32+32; ++tp){
        float a = al[tp];
        h2 e = u2h(encW[(size_t)tp*128 + dp]);
        c0 += a*(float)e.x; c1 += a*(float)e.y;
      }
      scr[tid*2]=c0; scr[tid*2+1]=c1;
    }
    __syncthreads();
    if (tid<128){
      float c0=0.f, c1=0.f;
      #pragma unroll
      for (int k=0;k<8;++k){ c0 += scr[(k*128+tid)*2]; c1 += scr[(k*128+tid)*2+1]; }
      h2 c; c.x=(_Float16)c0; c.y=(_Float16)c1;
      unsigned w = h2u(c);
      ((unsigned*)ctxh)[tid] = w;
      ((unsigned*)pstB)[(size_t)t*256 + 128 + tid] = w;   // p ctx half
    }
    __syncthreads();
    //==== S6: d = [hA, ctx] @ proj_w.T + proj_b ====
    {
      const uint4* xa = (ks<2) ? hA4 : ctx4;
      const int    kb = (ks<2) ? 0 : 32;
      float a=0.f;
      #pragma unroll 2
      for (int kq=ks*16; kq<ks*16+16; ++kq)
        a = d4dot(wPRJ[kq*256 + j], xa[kq-kb], a);
      scr[tid]=a;
    }
    __syncthreads();
    if (tid<256){
      float dv = scr[tid]+scr[256+tid]+scr[512+tid]+scr[768+tid] + proj_b[tid];
      df[tid]=dv; dh[tid]=(_Float16)dv;
    }
    __syncthreads();
    //==== S7: GRU1 + residual ====
    gemv6(wG1I, wG1H, dd4, h14, j, ks, scr, tid);
    __syncthreads();
    if (tid<256){
      float s0 = scr[tid*6+0]+scr[(256+tid)*6+0]+scr[(512+tid)*6+0]+scr[(768+tid)*6+0];
      float s1 = scr[tid*6+1]+scr[(256+tid)*6+1]+scr[(512+tid)*6+1]+scr[(768+tid)*6+1];
      float s2 = scr[tid*6+2]+scr[(256+tid)*6+2]+scr[(512+tid)*6+2]+scr[(768+tid)*6+2];
      float s3 = scr[tid*6+3]+scr[(256+tid)*6+3]+scr[(512+tid)*6+3]+scr[(768+tid)*6+3];
      float s4 = scr[tid*6+4]+scr[(256+tid)*6+4]+scr[(512+tid)*6+4]+scr[(768+tid)*6+4];
      float s5 = scr[tid*6+5]+scr[(256+tid)*6+5]+scr[(512+tid)*6+5]+scr[(768+tid)*6+5];
      float gir = s0 + g1_bih[tid];
      float giz = s1 + g1_bih[256+tid];
      float gin = s2 + g1_bih[512+tid];
      float ghr = s3 + g1_bhh[tid];
      float ghz = s4 + g1_bhh[256+tid];
      float ghn = s5 + g1_bhh[512+tid];
      float r = sigmf(gir+ghr), z = sigmf(giz+ghz);
      float n = tanhf_(gin + r*ghn);
      float h = (1.f-z)*n + z*h1f[tid];
      float dn = h + df[tid];
      h1f[tid]=h; h1h[tid]=(_Float16)h;
      df[tid]=dn; dh[tid]=(_Float16)dn;
    }
    __syncthreads();
    //==== S8: GRU2 + residual -> pst ====
    gemv6(wG2I, wG2H, dd4, h24, j, ks, scr, tid);
    __syncthreads();
    if (tid<256){
      float s0 = scr[tid*6+0]+scr[(256+tid)*6+0]+scr[(512+tid)*6+0]+scr[(768+tid)*6+0];
      float s1 = scr[tid*6+1]+scr[(256+tid)*6+1]+scr[(512+tid)*6+1]+scr[(768+tid)*6+1];
      float s2 = scr[tid*6+2]+scr[(256+tid)*6+2]+scr[(512+tid)*6+2]+scr[(768+tid)*6+2];
      float s3 = scr[tid*6+3]+scr[(256+tid)*6+3]+scr[(512+tid)*6+3]+scr[(768+tid)*6+3];
      float s4 = scr[tid*6+4]+scr[(256+tid)*6+4]+scr[(512+tid)*6+4]+scr[(768+tid)*6+4];
      float s5 = scr[tid*6+5]+scr[(256+tid)*6+5]+scr[(512+tid)*6+5]+scr[(768+tid)*6+5];
      float gir = s0 + g2_bih[tid];
      float giz = s1 + g2_bih[256+tid];
      float gin = s2 + g2_bih[512+tid];
      float ghr = s3 + g2_bhh[tid];
      float ghz = s4 + g2_bhh[256+tid];
      float ghn = s5 + g2_bhh[512+tid];
      float r = sigmf(gir+ghr), z = sigmf(giz+ghz);
      float n = tanhf_(gin + r*ghn);
      float h = (1.f-z)*n + z*h2f[tid];
      float dn = h + df[tid];
      h2f[tid]=h; h2h[tid]=(_Float16)h;
      pstB[(size_t)t*512 + tid] = (_Float16)dn;            // p d half
    }
    __syncthreads();
  }
}

// ---------------- K5: mel + stop projections ----------------
__global__ void k_post(const float* __restrict__ mel_b, const float* __restrict__ stop_w,
                       const float* __restrict__ stop_b, float* __restrict__ out,
                       char* __restrict__ ws){
  int bt = blockIdx.x;             // b*TD + t
  int b = bt / TD, t = bt % TD;
  int j = threadIdx.x;
  const h2* wm = (const h2*)(ws + OFF_W2) + A_MELW;
  const _Float16* p = (const _Float16*)(ws + OFF_P) + (size_t)bt*512;
  __shared__ _Float16 pl[512];
  ((uint32_t*)pl)[j] = ((const uint32_t*)p)[j];
  __syncthreads();
  const h2* p2 = (const h2*)pl;
  if (j < 160){
    float acc = mel_b[j];
    #pragma unroll 8
    for (int kp=0; kp<256; ++kp) acc = dot2f(wm[kp*160 + j], p2[kp], acc);
    out[(size_t)bt*MR + j] = acc;
  } else if (j == 160){
    float acc = stop_b[0];
    for (int k=0; k<512; ++k) acc += stop_w[k]*(float)pl[k];
    float s = __fdividef(1.f, 1.f + __expf(-acc));
    float* os = out + (size_t)NB*TD*MR + (size_t)NB*TD*TE + (size_t)b*2*TD;
    os[2*t]   = s;
    os[2*t+1] = s;
  }
}

// ---------------- host ----------------
extern "C" void kernel_launch(void* const* d_in, const int* in_sizes, int n_in,
                              void* d_out, int out_size, void* d_ws, size_t ws_size,
                              hipStream_t stream)
{
  const float* enc     = (const float*)d_in[0];
  const float* xin     = (const float*)d_in[1];
  const int*   mlen    = (const int*)  d_in[2];
  const float* pre_w1  = (const float*)d_in[3];
  const float* pre_b1  = (const float*)d_in[4];
  const float* pre_w2  = (const float*)d_in[5];
  const float* pre_b2  = (const float*)d_in[6];
  const float* mem_w   = (const float*)d_in[7];
  const float* att_wih = (const float*)d_in[8];
  const float* att_whh = (const float*)d_in[9];
  const float* att_bih = (const float*)d_in[10];
  const float* att_bhh = (const float*)d_in[11];
  const float* q_w     = (const float*)d_in[12];
  const float* v_w     = (const float*)d_in[13];
  const float* proj_w  = (const float*)d_in[14];
  const float* proj_b  = (const float*)d_in[15];
  const float* g1_wih  = (const float*)d_in[16];
  const float* g1_whh  = (const float*)d_in[17];
  const float* g1_bih  = (const float*)d_in[18];
  const float* g1_bhh  = (const float*)d_in[19];
  const float* g2_wih  = (const float*)d_in[20];
  const float* g2_whh  = (const float*)d_in[21];
  const float* g2_bih  = (const float*)d_in[22];
  const float* g2_bhh  = (const float*)d_in[23];
  const float* mel_w   = (const float*)d_in[24];
  const float* mel_b   = (const float*)d_in[25];
  const float* stop_w  = (const float*)d_in[26];
  const float* stop_b  = (const float*)d_in[27];
  (void)in_sizes; (void)n_in; (void)out_size;

  if (ws_size < WS_NEEDED) return;

  float* out = (float*)d_out;
  char*  ws  = (char*)d_ws;

  auto conv = [&](const float* src, size_t off_h2, int O, int Kh, int k0, int ld){
    int n = O*Kh;
    k_conv<<<(n+255)/256, 256, 0, stream>>>(src, ws, (unsigned)off_h2, O, Kh, k0, ld);
  };
  auto conv8 = [&](const float* src, size_t off16, int O, int Kq, int k0, int ld){
    int n = O*Kq;
    k_conv8<<<(n+255)/256, 256, 0, stream>>>(src, ws, (unsigned)off16, O, Kq, k0, ld);
  };

  // pool A (aux kernels)
  conv(pre_w1,  A_PW1,  256, 80,  0, 160);
  conv(pre_w2,  A_PW2,  128, 128, 0, 256);
  conv(att_wih, A_WIHP, 768, 64,  0, 384);
  conv(mem_w,   A_MEMW, 256, 128, 0, 256);
  conv(mel_w,   A_MELW, 160, 256, 0, 512);
  // pool B (decoder)
  conv8(att_wih, B_ATTC, 768, 32, 128, 384);
  conv8(att_whh, B_ATTH, 768, 32, 0,   256);
  conv8(g1_wih,  B_G1I,  768, 32, 0,   256);
  conv8(g1_whh,  B_G1H,  768, 32, 0,   256);
  conv8(g2_wih,  B_G2I,  768, 32, 0,   256);
  conv8(g2_whh,  B_G2H,  768, 32, 0,   256);
  conv8(proj_w,  B_PROJ, 256, 64, 0,   512);
  conv8(q_w,     B_QW,   256, 32, 0,   256);

  k_pm <<<NB*TE, 256, 0, stream>>>(enc, ws);
  k_pre<<<NB*TD, 256, 0, stream>>>(xin, pre_b1, pre_b2, att_bih, ws);
  k_dec<<<NB, 1024, 0, stream>>>(mlen, att_bhh, v_w, proj_b,
                                 g1_bih, g1_bhh, g2_bih, g2_bhh, out, ws);
  k_post<<<NB*TD, 256, 0, stream>>>(mel_b, stop_w, stop_b, out, ws);
}